// Round 2
// baseline (10041.933 us; speedup 1.0000x reference)
//
#include <hip/hip_runtime.h>
#include <math.h>

#define LRELU(v) ((v) >= 0.f ? (v) : 0.2f*(v))

__device__ __forceinline__ float sigmoidf_(float x){ return 1.f/(1.f + expf(-x)); }

// ---------------------------------------------------------------------------
// conv1: x (Nimg,1,128,128) -> e1 (Nimg,16,64,64), k3 s2 p1, bias+lrelu
// grid (16, Nimg), block 256. Each thread: one out px, all 16 oc.
// ---------------------------------------------------------------------------
__global__ __launch_bounds__(256) void k_conv1(const float* __restrict__ x,
    const float* __restrict__ W, const float* __restrict__ Bb, float* __restrict__ out)
{
    __shared__ float wl[144];
    __shared__ float bl[16];
    int tid = threadIdx.x;
    if (tid < 144) { int oc = tid/9, tap = tid%9; wl[tap*16+oc] = W[oc*9+tap]; }
    if (tid < 16) bl[tid] = Bb[tid];
    __syncthreads();
    int img = blockIdx.y;
    int px = blockIdx.x*256 + tid;
    int oy = px >> 6, ox = px & 63;
    const float* xin = x + (size_t)img*16384;
    float acc[16];
    #pragma unroll
    for (int o=0;o<16;++o) acc[o]=bl[o];
    #pragma unroll
    for (int kh=0; kh<3; ++kh){
        int iy = 2*oy + kh - 1;
        bool vy = (iy>=0 && iy<128);
        #pragma unroll
        for (int kw=0; kw<3; ++kw){
            int ix = 2*ox + kw - 1;
            float v = (vy && ix>=0 && ix<128) ? xin[iy*128+ix] : 0.f;
            int tap = kh*3+kw;
            #pragma unroll
            for (int o=0;o<16;++o) acc[o] += wl[tap*16+o]*v;
        }
    }
    float* op = out + (size_t)img*65536 + px;
    #pragma unroll
    for (int o=0;o<16;++o){ float v = acc[o]; op[o*4096] = LRELU(v); }
}

// ---------------------------------------------------------------------------
// conv2: e1 (Nimg,16,64,64) -> e2 (Nimg,64,32,32), k3 s2 p1, bias+lrelu
// grid (4 octiles of 16, Nimg), block 256. thread: 4 px x 16 oc.
// LDS tile per 2-ic chunk: [2][65][68] floats, c = ix+4.
// ---------------------------------------------------------------------------
__global__ __launch_bounds__(256) void k_conv2(const float* __restrict__ in,
    const float* __restrict__ W, const float* __restrict__ Bb, float* __restrict__ out)
{
    __shared__ float tile[2*65*68];
    __shared__ float wl[2*9*16];
    int tid = threadIdx.x;
    int img = blockIdx.y;
    int ocBase = blockIdx.x*16;
    int y = tid >> 3, xg = tid & 7, x0 = xg*4;
    float acc[16][4];
    #pragma unroll
    for (int o=0;o<16;++o){ float b = Bb[ocBase+o];
        #pragma unroll
        for (int p=0;p<4;++p) acc[o][p] = b; }
    const float* base = in + (size_t)img*65536;
    for (int icB=0; icB<16; icB+=2){
        for (int e=tid; e<2210; e+=256){            // 2*65*17 float4
            int c4 = e % 17; int rr = (e/17)%65; int ch = e/(17*65);
            int iy = rr - 1; int ixb = c4*4 - 4;
            float4 v = make_float4(0.f,0.f,0.f,0.f);
            if (iy>=0 && iy<64 && c4>=1)
                v = *(const float4*)(base + (icB+ch)*4096 + iy*64 + ixb);
            *(float4*)(&tile[ch*4420 + rr*68 + c4*4]) = v;
        }
        for (int e=tid; e<288; e+=256){
            int oc = e & 15; int rest = e >> 4; int tap = rest % 9; int ch = rest/9;
            wl[(ch*9+tap)*16 + oc] = W[((ocBase+oc)*16 + icB+ch)*9 + tap];
        }
        __syncthreads();
        #pragma unroll
        for (int ch=0; ch<2; ++ch){
            #pragma unroll
            for (int kh=0; kh<3; ++kh){
                int r = 2*y + kh;
                const float4* row = (const float4*)(&tile[ch*4420 + r*68 + 2*x0]);
                float4 a0=row[0], a1=row[1], a2=row[2];
                float win[12] = {a0.x,a0.y,a0.z,a0.w,a1.x,a1.y,a1.z,a1.w,a2.x,a2.y,a2.z,a2.w};
                #pragma unroll
                for (int kw=0; kw<3; ++kw){
                    const float4* wp = (const float4*)(&wl[(ch*9+kh*3+kw)*16]);
                    float4 w0=wp[0], w1=wp[1], w2=wp[2], w3=wp[3];
                    float wv[16] = {w0.x,w0.y,w0.z,w0.w,w1.x,w1.y,w1.z,w1.w,
                                    w2.x,w2.y,w2.z,w2.w,w3.x,w3.y,w3.z,w3.w};
                    #pragma unroll
                    for (int p=0;p<4;++p){
                        float v = win[2*p + kw + 3];
                        #pragma unroll
                        for (int o=0;o<16;++o) acc[o][p] += wv[o]*v;
                    }
                }
            }
        }
        __syncthreads();
    }
    float* op = out + (size_t)img*65536 + (size_t)ocBase*1024 + y*32 + x0;
    #pragma unroll
    for (int o=0;o<16;++o){
        float4 v = make_float4(LRELU(acc[o][0]),LRELU(acc[o][1]),LRELU(acc[o][2]),LRELU(acc[o][3]));
        *(float4*)(op + o*1024) = v;
    }
}

// ---------------------------------------------------------------------------
// conv5: 5x5 pad2 s1 over 32x32, input = concat(inA[icA ch], inB[rest]),
// partial sums over ic-splits into P[split][32][ocTot][1024] (no bias/act).
// grid (ocTot/8, 32, nsplit), block 128. thread: 8 px (one row seg) x 8 oc.
// LDS tile [4][36][44] (c = x+4, r = y+2); stride 44 -> bank-uniform b128 reads.
// ---------------------------------------------------------------------------
__global__ __launch_bounds__(128) void k_conv5(
    const float* __restrict__ inA, int icA, int strA,
    const float* __restrict__ inB, int strB,
    const float* __restrict__ W, int wIcTot, int wIcOff,
    int icTotal, int ocTot,
    float* __restrict__ P)
{
    __shared__ float tile[4*36*44];   // 6336 floats
    __shared__ float wl[4*25*8];      // 800 floats
    int tid = threadIdx.x;
    int b = blockIdx.y;
    int ocBase = blockIdx.x*8;
    int split = blockIdx.z, nsplit = gridDim.z;
    int icCount = icTotal / nsplit;
    int icStart = split * icCount;
    int y = tid >> 2, xg = tid & 3, x0 = xg*8;
    float acc[8][8];
    #pragma unroll
    for (int o=0;o<8;++o)
        #pragma unroll
        for (int p=0;p<8;++p) acc[o][p]=0.f;

    for (int cb=0; cb<icCount; cb+=4){
        for (int e=tid; e<1584; e+=128){           // 4*36*11 float4
            int c4 = e % 11; int rr = (e/11) % 36; int ch = e/(11*36);
            int j = icStart + cb + ch;
            int iy = rr - 2; int ixb = c4*4 - 4;
            float4 v = make_float4(0.f,0.f,0.f,0.f);
            if (iy>=0 && iy<32 && c4>=1 && c4<=8){
                const float* src = (j < icA) ? (inA + (size_t)b*strA + (size_t)j*1024)
                                             : (inB + (size_t)b*strB + (size_t)(j-icA)*1024);
                v = *(const float4*)(src + iy*32 + ixb);
            }
            *(float4*)(&tile[ch*1584 + rr*44 + c4*4]) = v;
        }
        for (int e=tid; e<800; e+=128){
            int oc = e & 7; int rest = e >> 3; int tap = rest % 25; int ch = rest/25;
            int j = icStart + cb + ch;
            wl[(ch*25+tap)*8 + oc] = W[((size_t)(ocBase+oc)*wIcTot + wIcOff + j)*25 + tap];
        }
        __syncthreads();
        #pragma unroll
        for (int ch=0; ch<4; ++ch){
            #pragma unroll
            for (int kh=0; kh<5; ++kh){
                const float4* row = (const float4*)(&tile[ch*1584 + (y+kh)*44 + x0]);
                float4 a0=row[0], a1=row[1], a2=row[2], a3=row[3];
                float win[16] = {a0.x,a0.y,a0.z,a0.w,a1.x,a1.y,a1.z,a1.w,
                                 a2.x,a2.y,a2.z,a2.w,a3.x,a3.y,a3.z,a3.w};
                #pragma unroll
                for (int kw=0; kw<5; ++kw){
                    const float4* wp = (const float4*)(&wl[(ch*25+kh*5+kw)*8]);
                    float4 wa = wp[0], wb = wp[1];
                    #pragma unroll
                    for (int p=0;p<8;++p){
                        float v = win[p+kw+2];
                        acc[0][p] += wa.x*v; acc[1][p] += wa.y*v;
                        acc[2][p] += wa.z*v; acc[3][p] += wa.w*v;
                        acc[4][p] += wb.x*v; acc[5][p] += wb.y*v;
                        acc[6][p] += wb.z*v; acc[7][p] += wb.w*v;
                    }
                }
            }
        }
        __syncthreads();
    }
    float* op = P + (((size_t)split*32 + b)*ocTot + ocBase)*1024 + y*32 + x0;
    #pragma unroll
    for (int o=0;o<8;++o){
        *(float4*)(op + o*1024 + 0) = make_float4(acc[o][0],acc[o][1],acc[o][2],acc[o][3]);
        *(float4*)(op + o*1024 + 4) = make_float4(acc[o][4],acc[o][5],acc[o][6],acc[o][7]);
    }
}

// ---------------------------------------------------------------------------
// combine zr: r=sig(P0+P1+b[0:64]), z=sig(..[64:128]); rh=r*h; store z.
// P: [2][32][128][1024]. grid 2048 x 256, one float4 per thread.
// ---------------------------------------------------------------------------
__global__ __launch_bounds__(256) void k_comb_zr(const float* __restrict__ P,
    const float* __restrict__ h, const float* __restrict__ bzr,
    float* __restrict__ rh, float* __restrict__ zout)
{
    int i = blockIdx.x*256 + threadIdx.x;      // over 32*64*256 float4
    int q = i & 255; int c = (i >> 8) & 63; int b = i >> 14;
    const float4* P4 = (const float4*)P;
    size_t ir = (((size_t)b*128) + c)*256 + q;
    size_t iz = (((size_t)b*128) + c + 64)*256 + q;
    size_t s1 = (size_t)32*128*256;
    float4 pr = P4[ir], pr2 = P4[ir + s1];
    float4 pz = P4[iz], pz2 = P4[iz + s1];
    float br = bzr[c], bz = bzr[c+64];
    size_t ii = ((size_t)b*64 + c)*256 + q;
    float4 hv = ((const float4*)h)[ii];
    float4 r, z;
    r.x = sigmoidf_(pr.x+pr2.x+br); r.y = sigmoidf_(pr.y+pr2.y+br);
    r.z = sigmoidf_(pr.z+pr2.z+br); r.w = sigmoidf_(pr.w+pr2.w+br);
    z.x = sigmoidf_(pz.x+pz2.x+bz); z.y = sigmoidf_(pz.y+pz2.y+bz);
    z.z = sigmoidf_(pz.z+pz2.z+bz); z.w = sigmoidf_(pz.w+pz2.w+bz);
    float4 rhv = make_float4(r.x*hv.x, r.y*hv.y, r.z*hv.z, r.w*hv.w);
    ((float4*)rh)[ii] = rhv;
    ((float4*)zout)[ii] = z;
}

// ---------------------------------------------------------------------------
// combine cand: cand=tanh(sum P[0..3]+bc); hn=(1-z)*h+z*cand -> h (and hs[t])
// P: [4][32][64][1024]. grid 2048 x 256.
// ---------------------------------------------------------------------------
__global__ __launch_bounds__(256) void k_comb_cand(const float* __restrict__ P,
    const float* __restrict__ h, const float* __restrict__ z, const float* __restrict__ bc,
    float* __restrict__ hout, float* __restrict__ hsout)
{
    int i = blockIdx.x*256 + threadIdx.x;
    int q = i & 255; int c = (i >> 8) & 63; int b = i >> 14;
    size_t ii = ((size_t)b*64 + c)*256 + q;
    size_t s = (size_t)32*64*256;
    const float4* P4 = (const float4*)P;
    float4 p0 = P4[ii], p1 = P4[ii+s], p2 = P4[ii+2*s], p3 = P4[ii+3*s];
    float bcv = bc[c];
    float4 hv = ((const float4*)h)[ii];
    float4 zv = ((const float4*)z)[ii];
    float4 hn;
    float cx = tanhf(p0.x+p1.x+p2.x+p3.x+bcv);
    float cy = tanhf(p0.y+p1.y+p2.y+p3.y+bcv);
    float cz = tanhf(p0.z+p1.z+p2.z+p3.z+bcv);
    float cw = tanhf(p0.w+p1.w+p2.w+p3.w+bcv);
    hn.x = (1.f-zv.x)*hv.x + zv.x*cx;
    hn.y = (1.f-zv.y)*hv.y + zv.y*cy;
    hn.z = (1.f-zv.z)*hv.z + zv.z*cz;
    hn.w = (1.f-zv.w)*hv.w + zv.w*cw;
    ((float4*)hout)[ii] = hn;
    if (hsout) ((float4*)hsout)[ii] = hn;
}

// ---------------------------------------------------------------------------
// deconv1: hs (Ntb,64,32,32) -> y1 (Ntb,32,64,64), k4 lhs_dil2 pad2, bias+lrelu
// grid (4 octiles, 2 sptiles, Ntb), block 256. waves 0-1: even out-x, 2-3: odd.
// thread: 8 out px (stride 2 in x) x 8 oc.
// ---------------------------------------------------------------------------
__global__ __launch_bounds__(256) void k_deconv1(const float* __restrict__ in,
    const float* __restrict__ W, const float* __restrict__ Bb, float* __restrict__ out)
{
    __shared__ float tile[4*18*44];  // 3168
    __shared__ float wl[4*16*8];     // 512
    int tid = threadIdx.x;
    int tb = blockIdx.z;
    int ocBase = blockIdx.x*8;
    int Y0 = blockIdx.y*32;
    int low = tid & 127;
    int par = tid >> 7;              // wave-uniform parity
    int y = low >> 2, xg = low & 3, x0 = xg*16;
    int oy = Y0 + y;
    int ph = y & 1;
    int r0 = (y+1) >> 1;
    float acc[8][8];
    #pragma unroll
    for (int o=0;o<8;++o)
        #pragma unroll
        for (int j=0;j<8;++j) acc[o][j]=0.f;
    const float* base = in + (size_t)tb*65536;
    int iyBase = Y0/2 - 1;
    for (int icB=0; icB<64; icB+=4){
        for (int e=tid; e<792; e+=256){            // 4*18*11 float4
            int c4 = e % 11; int rr = (e/11)%18; int ch = e/(11*18);
            int iy = iyBase + rr; int ixb = c4*4 - 4;
            float4 v = make_float4(0.f,0.f,0.f,0.f);
            if (iy>=0 && iy<32 && c4>=1 && c4<=8)
                v = *(const float4*)(base + (icB+ch)*1024 + iy*32 + ixb);
            *(float4*)(&tile[ch*792 + rr*44 + c4*4]) = v;
        }
        for (int e=tid; e<512; e+=256){
            int oc = e & 7; int rest = e >> 3; int tap = rest & 15; int ch = rest >> 4;
            wl[(ch*16+tap)*8+oc] = W[(((ocBase+oc)*64) + icB+ch)*16 + tap];
        }
        __syncthreads();
        #pragma unroll
        for (int ch=0; ch<4; ++ch){
            const float4* ra = (const float4*)(&tile[ch*792 + r0*44 + 8*xg]);
            float4 a0=ra[0],a1=ra[1],a2=ra[2],a3=ra[3];
            const float4* rb = (const float4*)(&tile[ch*792 + (r0+1)*44 + 8*xg]);
            float4 b0=rb[0],b1=rb[1],b2=rb[2],b3=rb[3];
            float wa[16]={a0.x,a0.y,a0.z,a0.w,a1.x,a1.y,a1.z,a1.w,
                          a2.x,a2.y,a2.z,a2.w,a3.x,a3.y,a3.z,a3.w};
            float wb[16]={b0.x,b0.y,b0.z,b0.w,b1.x,b1.y,b1.z,b1.w,
                          b2.x,b2.y,b2.z,b2.w,b3.x,b3.y,b3.z,b3.w};
            if (par == 0){
                const float4* wp;
                wp = (const float4*)(&wl[(ch*16+ph*4+0)*8]);     float4 wA0=wp[0], wA1=wp[1];
                wp = (const float4*)(&wl[(ch*16+ph*4+2)*8]);     float4 wB0=wp[0], wB1=wp[1];
                wp = (const float4*)(&wl[(ch*16+(ph+2)*4+0)*8]); float4 wC0=wp[0], wC1=wp[1];
                wp = (const float4*)(&wl[(ch*16+(ph+2)*4+2)*8]); float4 wD0=wp[0], wD1=wp[1];
                #pragma unroll
                for (int j=0;j<8;++j){
                    float v0 = wa[j+3], v1 = wa[j+4], v2 = wb[j+3], v3 = wb[j+4];
                    acc[0][j] += wA0.x*v0 + wB0.x*v1 + wC0.x*v2 + wD0.x*v3;
                    acc[1][j] += wA0.y*v0 + wB0.y*v1 + wC0.y*v2 + wD0.y*v3;
                    acc[2][j] += wA0.z*v0 + wB0.z*v1 + wC0.z*v2 + wD0.z*v3;
                    acc[3][j] += wA0.w*v0 + wB0.w*v1 + wC0.w*v2 + wD0.w*v3;
                    acc[4][j] += wA1.x*v0 + wB1.x*v1 + wC1.x*v2 + wD1.x*v3;
                    acc[5][j] += wA1.y*v0 + wB1.y*v1 + wC1.y*v2 + wD1.y*v3;
                    acc[6][j] += wA1.z*v0 + wB1.z*v1 + wC1.z*v2 + wD1.z*v3;
                    acc[7][j] += wA1.w*v0 + wB1.w*v1 + wC1.w*v2 + wD1.w*v3;
                }
            } else {
                const float4* wp;
                wp = (const float4*)(&wl[(ch*16+ph*4+1)*8]);     float4 wA0=wp[0], wA1=wp[1];
                wp = (const float4*)(&wl[(ch*16+ph*4+3)*8]);     float4 wB0=wp[0], wB1=wp[1];
                wp = (const float4*)(&wl[(ch*16+(ph+2)*4+1)*8]); float4 wC0=wp[0], wC1=wp[1];
                wp = (const float4*)(&wl[(ch*16+(ph+2)*4+3)*8]); float4 wD0=wp[0], wD1=wp[1];
                #pragma unroll
                for (int j=0;j<8;++j){
                    float v0 = wa[j+4], v1 = wa[j+5], v2 = wb[j+4], v3 = wb[j+5];
                    acc[0][j] += wA0.x*v0 + wB0.x*v1 + wC0.x*v2 + wD0.x*v3;
                    acc[1][j] += wA0.y*v0 + wB0.y*v1 + wC0.y*v2 + wD0.y*v3;
                    acc[2][j] += wA0.z*v0 + wB0.z*v1 + wC0.z*v2 + wD0.z*v3;
                    acc[3][j] += wA0.w*v0 + wB0.w*v1 + wC0.w*v2 + wD0.w*v3;
                    acc[4][j] += wA1.x*v0 + wB1.x*v1 + wC1.x*v2 + wD1.x*v3;
                    acc[5][j] += wA1.y*v0 + wB1.y*v1 + wC1.y*v2 + wD1.y*v3;
                    acc[6][j] += wA1.z*v0 + wB1.z*v1 + wC1.z*v2 + wD1.z*v3;
                    acc[7][j] += wA1.w*v0 + wB1.w*v1 + wC1.w*v2 + wD1.w*v3;
                }
            }
        }
        __syncthreads();
    }
    float* op = out + (size_t)tb*131072 + (size_t)ocBase*4096 + oy*64 + x0 + par;
    #pragma unroll
    for (int o=0;o<8;++o){
        float bv = Bb[ocBase+o];
        #pragma unroll
        for (int j=0;j<8;++j){
            float v = acc[o][j] + bv;
            op[o*4096 + 2*j] = LRELU(v);
        }
    }
}

// ---------------------------------------------------------------------------
// deconv2: y1 (Ntb,32,64,64) -> out (B,T,1,128,128) with tb=tbOff+local,
// (t,b)->(b,t) permute, k4 lhs_dil2 pad2, bias only. grid (16, Ntb), block 256.
// ---------------------------------------------------------------------------
__global__ __launch_bounds__(256) void k_deconv2(const float* __restrict__ in,
    const float* __restrict__ W, const float* __restrict__ Bb, float* __restrict__ out,
    int tbOff)
{
    __shared__ float wl[512];
    int tid = threadIdx.x;
    for (int e=tid; e<512; e+=256) wl[e] = W[e];   // [ic][kh][kw], oc=1
    __syncthreads();
    int tbl = blockIdx.y;
    int tb = tbOff + tbl; int t = tb >> 5; int b = tb & 31;
    int idx4 = blockIdx.x*256 + tid;
    int oy = idx4 >> 5; int ox0 = (idx4 & 31)*4;
    int ph = oy & 1;
    const float* base = in + (size_t)tbl*131072;
    float acc0=0.f, acc1=0.f, acc2=0.f, acc3=0.f;
    int ix0 = ox0/2 - 1;
    for (int ic=0; ic<32; ++ic){
        const float* cp = base + ic*4096;
        #pragma unroll
        for (int kk=0; kk<2; ++kk){
            int kh = ph + 2*kk;
            int iy = (oy + kh - 2) >> 1;
            if (iy < 0 || iy > 63) continue;
            const float* rp = cp + (size_t)iy*64;
            float wv0 = (ix0 >= 0)   ? rp[ix0]   : 0.f;
            float wv1 = rp[ix0+1];
            float wv2 = rp[ix0+2];
            float wv3 = (ix0+3 <= 63) ? rp[ix0+3] : 0.f;
            float w0 = wl[ic*16 + kh*4 + 0];
            float w1 = wl[ic*16 + kh*4 + 1];
            float w2 = wl[ic*16 + kh*4 + 2];
            float w3 = wl[ic*16 + kh*4 + 3];
            acc0 += w0*wv0 + w2*wv1;        // p=0: kw 0,2
            acc2 += w0*wv1 + w2*wv2;        // p=2
            acc1 += w1*wv1 + w3*wv2;        // p=1: kw 1,3
            acc3 += w1*wv2 + w3*wv3;        // p=3
        }
    }
    float bv = Bb[0];
    float4 res = make_float4(acc0+bv, acc1+bv, acc2+bv, acc3+bv);
    float* op = out + ((size_t)(b*10 + t))*16384 + (size_t)oy*128 + ox0;
    *(float4*)op = res;
}

// ---------------------------------------------------------------------------
// Workspace layout (bytes) — peak 142,606,336 B (136 MiB):
//   [0          ,  83886080): e2 (encoder input stack)  /  hs (decoder outputs)
//   [83886080   ,  92274688): h
//   [92274688   , 100663296): zb
//   [100663296  , 109051904): rh
//   [109051904  , 142606336): P (shared by Pzr [2][32][128][1024] and
//                                Pc [4][32][64][1024], disjoint lifetimes)
//   Phase 1: e1 chunk (40 MB) overlays [83886080, 125829120) (h/zb/rh/P not
//            yet live; h memset happens AFTER phase 1).
//   Phase 4: y1 chunk (40 MB) overlays same region (h/zb/rh/P dead).
// ---------------------------------------------------------------------------
extern "C" void kernel_launch(void* const* d_in, const int* in_sizes, int n_in,
                              void* d_out, int out_size, void* d_ws, size_t ws_size,
                              hipStream_t stream)
{
    const float* x    = (const float*)d_in[0];
    const float* ew1  = (const float*)d_in[1];
    const float* eb1  = (const float*)d_in[2];
    const float* ew2  = (const float*)d_in[3];
    const float* eb2  = (const float*)d_in[4];
    const float* ewzr = (const float*)d_in[5];
    const float* ebzr = (const float*)d_in[6];
    const float* ewc  = (const float*)d_in[7];
    const float* ebc  = (const float*)d_in[8];
    const float* dwzr = (const float*)d_in[9];
    const float* dbzr = (const float*)d_in[10];
    const float* dwc  = (const float*)d_in[11];
    const float* dbc  = (const float*)d_in[12];
    const float* dw1  = (const float*)d_in[13];
    const float* db1  = (const float*)d_in[14];
    const float* dw2  = (const float*)d_in[15];
    const float* db2  = (const float*)d_in[16];
    float* out = (float*)d_out;
    char* ws = (char*)d_ws;

    float* e2  = (float*)(ws + 0);
    float* h   = (float*)(ws + 83886080UL);
    float* zb  = (float*)(ws + 92274688UL);
    float* rh  = (float*)(ws + 100663296UL);
    float* P   = (float*)(ws + 109051904UL);
    float* e1c = (float*)(ws + 83886080UL);   // phase-1 overlay (40 MB)
    float* hs  = e2;                          // decoder overlay of e2
    float* y1c = (float*)(ws + 83886080UL);   // phase-4 overlay (40 MB)

    // Phase 1: conv1 -> conv2, chunked x2 over images (160 each)
    for (int c=0; c<2; ++c){
        int off = c*160;
        k_conv1<<<dim3(16,160),256,0,stream>>>(x + (size_t)off*16384, ew1, eb1, e1c);
        k_conv2<<<dim3(4,160),256,0,stream>>>(e1c, ew2, eb2, e2 + (size_t)off*65536);
    }

    hipMemsetAsync(h, 0, 8388608UL, stream);    // h0 = zeros (after e1c overlay dies)

    // Phase 2: encoder GRU scan
    for (int t=0; t<10; ++t){
        k_conv5<<<dim3(16,32,2),128,0,stream>>>(e2 + (size_t)t*65536, 64, 655360,
                                                h, 65536, ewzr, 128, 0, 128, 128, P);
        k_comb_zr<<<2048,256,0,stream>>>(P, h, ebzr, rh, zb);
        k_conv5<<<dim3(8,32,4),128,0,stream>>>(e2 + (size_t)t*65536, 64, 655360,
                                               rh, 65536, ewc, 128, 0, 128, 64, P);
        k_comb_cand<<<2048,256,0,stream>>>(P, h, zb, ebc, h, nullptr);
    }
    // Phase 3: decoder GRU scan (weight ic slice [64:128]); hs overlays e2
    for (int t=0; t<10; ++t){
        k_conv5<<<dim3(16,32,2),128,0,stream>>>(h, 64, 65536, nullptr, 0,
                                                dwzr, 128, 64, 64, 128, P);
        k_comb_zr<<<2048,256,0,stream>>>(P, h, dbzr, rh, zb);
        k_conv5<<<dim3(8,32,4),128,0,stream>>>(rh, 64, 65536, nullptr, 0,
                                               dwc, 128, 64, 64, 64, P);
        k_comb_cand<<<2048,256,0,stream>>>(P, h, zb, dbc, h, hs + (size_t)t*2097152);
    }
    // Phase 4: deconv1 -> deconv2, chunked x4 over tb (80 each)
    for (int c=0; c<4; ++c){
        int tbOff = c*80;
        k_deconv1<<<dim3(4,2,80),256,0,stream>>>(hs + (size_t)tbOff*65536, dw1, db1, y1c);
        k_deconv2<<<dim3(16,80),256,0,stream>>>(y1c, dw2, db2, out, tbOff);
    }
}